// Round 1
// baseline (135.861 us; speedup 1.0000x reference)
//
#include <hip/hip_runtime.h>
#include <hip/hip_bf16.h>

#define N_TOK 8192
#define DIM   1024
#define DH    64
#define NWARP 8
#define QT    16
#define KVT   32

typedef float f32x4  __attribute__((ext_vector_type(4)));
typedef short bf16x8 __attribute__((ext_vector_type(8)));

__device__ inline short f2bf(float f) {
    union { __hip_bfloat16 h; short s; } u;
    u.h = __float2bfloat16(f);
    return u.s;
}

// ---------------- kernel 0: weight convert/transpose ----------------
__global__ void conv_kernel(const float* __restrict__ Wqkv,
                            const float* __restrict__ Wout,
                            __hip_bfloat16* __restrict__ Wt,      // [192][1024]
                            __hip_bfloat16* __restrict__ WoT) {   // [1024][64]
    int idx = blockIdx.x * 256 + threadIdx.x;
    if (idx < 192 * 1024) {
        int n = idx >> 10, k = idx & 1023;
        Wt[idx] = __float2bfloat16(Wqkv[k * 192 + n]);
    } else {
        int j = idx - 192 * 1024;
        if (j < 1024 * 64) {
            int n = j >> 6, k = j & 63;
            WoT[j] = __float2bfloat16(Wout[k * 1024 + n]);
        }
    }
}

// ---------------- kernel 1: qkv = x @ Wqkv -------------------------
// grid 128, block 256 (4 waves x 16 rows = 64 rows/block), N=192 full width
__global__ __launch_bounds__(256) void qkv_kernel(
    const float* __restrict__ x,
    const __hip_bfloat16* __restrict__ Wt,
    __hip_bfloat16* __restrict__ Qb,    // [8192][64], pre-scaled by 1/8
    __hip_bfloat16* __restrict__ Kb,    // [8192][64]
    __hip_bfloat16* __restrict__ Vt) {  // [64][8192] transposed
    const int tid = threadIdx.x;
    const int w = tid >> 6, lane = tid & 63;
    const int l16 = lane & 15, lq = lane >> 4;
    const int m0 = blockIdx.x * 64 + w * 16;

    f32x4 acc[12];
    for (int i = 0; i < 12; ++i) acc[i] = (f32x4)0.f;

    const float* xrow = x + (size_t)(m0 + l16) * DIM;
    for (int ks = 0; ks < 32; ++ks) {
        int kb = ks * 32 + 8 * lq;
        float4 f0 = *reinterpret_cast<const float4*>(xrow + kb);
        float4 f1 = *reinterpret_cast<const float4*>(xrow + kb + 4);
        bf16x8 a;
        a[0] = f2bf(f0.x); a[1] = f2bf(f0.y); a[2] = f2bf(f0.z); a[3] = f2bf(f0.w);
        a[4] = f2bf(f1.x); a[5] = f2bf(f1.y); a[6] = f2bf(f1.z); a[7] = f2bf(f1.w);
        for (int nt = 0; nt < 12; ++nt) {
            bf16x8 b = *reinterpret_cast<const bf16x8*>(Wt + (size_t)(nt * 16 + l16) * DIM + kb);
            acc[nt] = __builtin_amdgcn_mfma_f32_16x16x32_bf16(a, b, acc[nt], 0, 0, 0);
        }
    }
    for (int nt = 0; nt < 12; ++nt) {
        int col = nt * 16 + l16;
        for (int r = 0; r < 4; ++r) {
            int row = m0 + 4 * lq + r;
            float v = acc[nt][r];
            if (col < 64)        Qb[(size_t)row * DH + col] = __float2bfloat16(v * 0.125f);
            else if (col < 128)  Kb[(size_t)row * DH + (col - 64)] = __float2bfloat16(v);
            else                 Vt[(size_t)(col - 128) * N_TOK + row] = __float2bfloat16(v);
        }
    }
}

// ---------------- kernel 2: causal flash attention -----------------
// grid 256, block 512 (8 waves). Block b handles q-tiles b and 511-b.
// Each wave: 16 q rows, strided over 32-wide kv tiles, private online softmax.
__global__ __launch_bounds__(512) void attn_kernel(
    const __hip_bfloat16* __restrict__ Qb,
    const __hip_bfloat16* __restrict__ Kb,
    const __hip_bfloat16* __restrict__ Vt,
    __hip_bfloat16* __restrict__ Ob) {  // [8192][64]
    __shared__ __hip_bfloat16 sP[NWARP][QT][40];  // padded stride (80B, 16B-aligned frags)
    __shared__ float sO[NWARP][QT][DH];
    __shared__ float sM[NWARP][QT];
    __shared__ float sL[NWARP][QT];

    const int tid = threadIdx.x;
    const int w = tid >> 6, lane = tid & 63;
    const int l16 = lane & 15, lq = lane >> 4;
    const int b = blockIdx.x;

    for (int qi = 0; qi < 2; ++qi) {
        const int qt = (qi == 0) ? b : (511 - b);
        const int q0 = qt * QT;
        const int ntiles = ((q0 + QT - 1) >> 5) + 1;

        // preload Q fragments (16 rows x 64 dims)
        const __hip_bfloat16* qrow = Qb + (size_t)(q0 + l16) * DH;
        bf16x8 qf0 = *reinterpret_cast<const bf16x8*>(qrow + 8 * lq);
        bf16x8 qf1 = *reinterpret_cast<const bf16x8*>(qrow + 32 + 8 * lq);

        float m[4], lsum[4];
        f32x4 Oacc[4];
        for (int r = 0; r < 4; ++r) { m[r] = -3.0e38f; lsum[r] = 0.f; }
        for (int dt = 0; dt < 4; ++dt) Oacc[dt] = (f32x4)0.f;

        for (int t = w; t < ntiles; t += NWARP) {
            const int kv0 = t * KVT;
            // S = Q K^T  (16 x 32), two 16-wide N subtiles
            f32x4 S[2];
            for (int nt = 0; nt < 2; ++nt) {
                const __hip_bfloat16* krow = Kb + (size_t)(kv0 + nt * 16 + l16) * DH;
                bf16x8 k0 = *reinterpret_cast<const bf16x8*>(krow + 8 * lq);
                bf16x8 k1 = *reinterpret_cast<const bf16x8*>(krow + 32 + 8 * lq);
                f32x4 s = (f32x4)0.f;
                s = __builtin_amdgcn_mfma_f32_16x16x32_bf16(qf0, k0, s, 0, 0, 0);
                s = __builtin_amdgcn_mfma_f32_16x16x32_bf16(qf1, k1, s, 0, 0, 0);
                S[nt] = s;
            }
            // causal mask (C layout: col = l16 -> kv, row = 4*lq+r -> q)
            for (int nt = 0; nt < 2; ++nt) {
                int kv = kv0 + nt * 16 + l16;
                for (int r = 0; r < 4; ++r) {
                    int q = q0 + 4 * lq + r;
                    if (kv > q) S[nt][r] = -1.0e30f;
                }
            }
            // online softmax, per q-row (reduce across 16-lane groups)
            for (int r = 0; r < 4; ++r) {
                float mx = fmaxf(S[0][r], S[1][r]);
                for (int off = 1; off < 16; off <<= 1)
                    mx = fmaxf(mx, __shfl_xor(mx, off));
                float mnew = fmaxf(m[r], mx);
                float fac = __expf(m[r] - mnew);
                float p0 = __expf(S[0][r] - mnew);
                float p1 = __expf(S[1][r] - mnew);
                float ps = p0 + p1;
                for (int off = 1; off < 16; off <<= 1)
                    ps += __shfl_xor(ps, off);
                lsum[r] = lsum[r] * fac + ps;
                m[r] = mnew;
                sP[w][4 * lq + r][l16]      = __float2bfloat16(p0);
                sP[w][4 * lq + r][16 + l16] = __float2bfloat16(p1);
                for (int dt = 0; dt < 4; ++dt) Oacc[dt][r] *= fac;
            }
            // PV: A = P (16x32) from LDS transpose, B = Vt rows
            bf16x8 pf = *reinterpret_cast<const bf16x8*>(&sP[w][l16][8 * lq]);
            for (int dt = 0; dt < 4; ++dt) {
                bf16x8 vf = *reinterpret_cast<const bf16x8*>(
                    Vt + (size_t)(dt * 16 + l16) * N_TOK + kv0 + 8 * lq);
                Oacc[dt] = __builtin_amdgcn_mfma_f32_16x16x32_bf16(pf, vf, Oacc[dt], 0, 0, 0);
            }
        }

        // write per-wave partials
        if (l16 == 0) {
            for (int r = 0; r < 4; ++r) {
                sM[w][4 * lq + r] = m[r];
                sL[w][4 * lq + r] = lsum[r];
            }
        }
        for (int dt = 0; dt < 4; ++dt)
            for (int r = 0; r < 4; ++r)
                sO[w][4 * lq + r][dt * 16 + l16] = Oacc[dt][r];
        __syncthreads();

        // merge 8 partials, normalize, store
        for (int e = tid; e < QT * DH; e += 512) {
            int row = e >> 6, col = e & 63;
            float mt = -3.0e38f;
            for (int wi = 0; wi < NWARP; ++wi) mt = fmaxf(mt, sM[wi][row]);
            float lt = 0.f, ot = 0.f;
            for (int wi = 0; wi < NWARP; ++wi) {
                float sc = __expf(sM[wi][row] - mt);
                lt += sL[wi][row] * sc;
                ot += sO[wi][row][col] * sc;
            }
            Ob[(size_t)(q0 + row) * DH + col] = __float2bfloat16(ot / lt);
        }
        __syncthreads();
    }
}

// ---------------- kernel 3: out = O @ Wout + bout ------------------
// grid (128, 4), block 256 (4 waves x 16 rows), BN = 256
__global__ __launch_bounds__(256) void out_kernel(
    const __hip_bfloat16* __restrict__ Ob,
    const __hip_bfloat16* __restrict__ WoT,
    const float* __restrict__ bout,
    float* __restrict__ out) {
    const int tid = threadIdx.x;
    const int w = tid >> 6, lane = tid & 63;
    const int l16 = lane & 15, lq = lane >> 4;
    const int m0 = blockIdx.x * 64 + w * 16;
    const int n0 = blockIdx.y * 256;

    const __hip_bfloat16* orow = Ob + (size_t)(m0 + l16) * DH;
    bf16x8 a0 = *reinterpret_cast<const bf16x8*>(orow + 8 * lq);
    bf16x8 a1 = *reinterpret_cast<const bf16x8*>(orow + 32 + 8 * lq);

    for (int nt = 0; nt < 16; ++nt) {
        const __hip_bfloat16* wrow = WoT + (size_t)(n0 + nt * 16 + l16) * DH;
        bf16x8 b0 = *reinterpret_cast<const bf16x8*>(wrow + 8 * lq);
        bf16x8 b1 = *reinterpret_cast<const bf16x8*>(wrow + 32 + 8 * lq);
        f32x4 acc = (f32x4)0.f;
        acc = __builtin_amdgcn_mfma_f32_16x16x32_bf16(a0, b0, acc, 0, 0, 0);
        acc = __builtin_amdgcn_mfma_f32_16x16x32_bf16(a1, b1, acc, 0, 0, 0);
        int col = n0 + nt * 16 + l16;
        float bb = bout[col];
        for (int r = 0; r < 4; ++r) {
            int row = m0 + 4 * lq + r;
            out[(size_t)row * 1024 + col] = acc[r] + bb;
        }
    }
}

// ---------------- launch -------------------------------------------
extern "C" void kernel_launch(void* const* d_in, const int* in_sizes, int n_in,
                              void* d_out, int out_size, void* d_ws, size_t ws_size,
                              hipStream_t stream) {
    const float* x    = (const float*)d_in[0];
    const float* Wqkv = (const float*)d_in[1];
    const float* Wout = (const float*)d_in[2];
    const float* bout = (const float*)d_in[3];
    float* out = (float*)d_out;

    char* ws = (char*)d_ws;
    __hip_bfloat16* Wt  = (__hip_bfloat16*)(ws);                 // 192*1024*2 = 393216
    __hip_bfloat16* WoT = (__hip_bfloat16*)(ws + 393216);        // 1024*64*2  = 131072
    __hip_bfloat16* Qb  = (__hip_bfloat16*)(ws + 524288);        // 1 MiB
    __hip_bfloat16* Kb  = (__hip_bfloat16*)(ws + 1572864);       // 1 MiB
    __hip_bfloat16* Vt  = (__hip_bfloat16*)(ws + 2621440);       // 1 MiB
    __hip_bfloat16* Ob  = (__hip_bfloat16*)(ws + 3670016);       // 1 MiB

    conv_kernel<<<1024, 256, 0, stream>>>(Wqkv, Wout, Wt, WoT);
    qkv_kernel<<<128, 256, 0, stream>>>(x, Wt, Qb, Kb, Vt);
    attn_kernel<<<256, 512, 0, stream>>>(Qb, Kb, Vt, Ob);
    out_kernel<<<dim3(128, 4), 256, 0, stream>>>(Ob, WoT, bout, out);
}

// Round 2
// 94.081 us; speedup vs baseline: 1.4441x; 1.4441x over previous
//
#include <hip/hip_runtime.h>
#include <hip/hip_bf16.h>

#define N_TOK 8192

typedef float f32x4  __attribute__((ext_vector_type(4)));
typedef float f32x16 __attribute__((ext_vector_type(16)));
typedef short bf16x8 __attribute__((ext_vector_type(8)));
typedef unsigned int u32x4 __attribute__((ext_vector_type(4)));

__device__ inline short f2bf(float f) {
    union { __hip_bfloat16 h; short s; } u;
    u.h = __float2bfloat16(f);
    return u.s;
}
__device__ inline unsigned cvtpk(float lo, float hi) {
    unsigned r;
    asm("v_cvt_pk_bf16_f32 %0, %1, %2" : "=v"(r) : "v"(lo), "v"(hi));
    return r;
}
__device__ inline void plswap(unsigned &a, unsigned &b) {
    asm("v_permlane32_swap_b32 %0, %1" : "+v"(a), "+v"(b));
}

// ---------------- kernel 0: weight convert/transpose ----------------
__global__ void conv_kernel(const float* __restrict__ Wqkv,
                            const float* __restrict__ Wout,
                            __hip_bfloat16* __restrict__ Wt,      // [192][1024]
                            __hip_bfloat16* __restrict__ WoT) {   // [1024][64]
    int idx = blockIdx.x * 256 + threadIdx.x;
    if (idx < 192 * 1024) {
        int n = idx >> 10, k = idx & 1023;
        Wt[idx] = __float2bfloat16(Wqkv[k * 192 + n]);
    } else {
        int j = idx - 192 * 1024;
        if (j < 1024 * 64) {
            int n = j >> 6, k = j & 63;
            WoT[j] = __float2bfloat16(Wout[k * 1024 + n]);
        }
    }
}

// ---------------- kernel 1: qkv = x @ Wqkv -------------------------
// grid 256, block 256 (4 waves: wr=row-half, wn=n-half). 32 rows/block.
// Q pre-scaled by 0.125*log2(e) (softmax done base-2).
__global__ __launch_bounds__(256) void qkv_kernel(
    const float* __restrict__ x,
    const __hip_bfloat16* __restrict__ Wt,
    __hip_bfloat16* __restrict__ Qb,    // [8192][64]
    __hip_bfloat16* __restrict__ Kb,    // [8192][64]
    __hip_bfloat16* __restrict__ Vt) {  // [64][8192]
    __shared__ __hip_bfloat16 sV[64][40];
    const int tid = threadIdx.x;
    const int w = tid >> 6, lane = tid & 63;
    const int l16 = lane & 15, lq = lane >> 4;
    const int wr = w & 1, wn = w >> 1;
    const int m0 = blockIdx.x * 32 + wr * 16;

    f32x4 acc[6];
    #pragma unroll
    for (int j = 0; j < 6; ++j) acc[j] = (f32x4)0.f;

    const float* xrow = x + (size_t)(m0 + l16) * 1024;
    for (int ks = 0; ks < 32; ++ks) {
        const int kb = ks * 32 + 8 * lq;
        float4 f0 = *reinterpret_cast<const float4*>(xrow + kb);
        float4 f1 = *reinterpret_cast<const float4*>(xrow + kb + 4);
        bf16x8 a;
        a[0]=f2bf(f0.x); a[1]=f2bf(f0.y); a[2]=f2bf(f0.z); a[3]=f2bf(f0.w);
        a[4]=f2bf(f1.x); a[5]=f2bf(f1.y); a[6]=f2bf(f1.z); a[7]=f2bf(f1.w);
        #pragma unroll
        for (int j = 0; j < 6; ++j) {
            bf16x8 b = *reinterpret_cast<const bf16x8*>(
                Wt + (size_t)((wn * 6 + j) * 16 + l16) * 1024 + kb);
            acc[j] = __builtin_amdgcn_mfma_f32_16x16x32_bf16(a, b, acc[j], 0, 0, 0);
        }
    }
    #pragma unroll
    for (int j = 0; j < 6; ++j) {
        const int nt = wn * 6 + j;
        const int col = nt * 16 + l16;
        #pragma unroll
        for (int r = 0; r < 4; ++r) {
            const int row = m0 + 4 * lq + r;
            float v = acc[j][r];
            if (nt < 4)      Qb[(size_t)row * 64 + col] = __float2bfloat16(v * 0.18033688011112042f);
            else if (nt < 8) Kb[(size_t)row * 64 + (col - 64)] = __float2bfloat16(v);
            else             sV[col - 128][row & 31] = __float2bfloat16(v);
        }
    }
    __syncthreads();
    const int vc = tid >> 2, vi = tid & 3;
    bf16x8 vv = *reinterpret_cast<const bf16x8*>(&sV[vc][vi * 8]);
    *reinterpret_cast<bf16x8*>(Vt + (size_t)vc * N_TOK + blockIdx.x * 32 + vi * 8) = vv;
}

// ---------------- kernel 2: causal flash attention -----------------
// grid 256: block = (pair p = bid>>1, split s = bid&1). Tiles p and 255-p.
// 8 waves, each owns full 32-q tile, kv chunks of 64 strided: c = 2w+s + 16i.
// Swapped QK^T (S^T = K Q^T): lane owns q-column, kv register-local.
__global__ __launch_bounds__(512) void attn_kernel(
    const __hip_bfloat16* __restrict__ Qb,
    const __hip_bfloat16* __restrict__ Kb,
    const __hip_bfloat16* __restrict__ Vt,
    float* __restrict__ Part) {  // [256 tiles][2 splits][2112] f32
    __shared__ float sO[8][64][32];
    __shared__ float sM[8][32];
    __shared__ float sL[8][32];
    const int tid = threadIdx.x;
    const int w = tid >> 6, lane = tid & 63;
    const int l31 = lane & 31, hi = lane >> 5;
    const int p = blockIdx.x >> 1, s = blockIdx.x & 1;

    for (int ti = 0; ti < 2; ++ti) {
        const int t = ti ? (255 - p) : p;
        const int q0 = t * 32;
        const int Ct = (q0 + 95) >> 6;   // ceil((q0+32)/64)
        const int qabs = q0 + l31;

        bf16x8 qf[4];
        const __hip_bfloat16* qrow = Qb + (size_t)(q0 + l31) * 64 + 8 * hi;
        #pragma unroll
        for (int c = 0; c < 4; ++c)
            qf[c] = *reinterpret_cast<const bf16x8*>(qrow + c * 16);

        float m = -3.0e38f, l = 0.f;
        f32x16 Oa = (f32x16)0.f, Oc = (f32x16)0.f;

        for (int c = 2 * w + s; c < Ct; c += 16) {
            const int kv0 = c * 64;
            const __hip_bfloat16* kbase = Kb + (size_t)(kv0 + l31) * 64 + 8 * hi;
            bf16x8 ka[4], kb2[4];
            #pragma unroll
            for (int kc = 0; kc < 4; ++kc) {
                ka[kc]  = *reinterpret_cast<const bf16x8*>(kbase + kc * 16);
                kb2[kc] = *reinterpret_cast<const bf16x8*>(kbase + 32 * 64 + kc * 16);
            }
            f32x16 Sa = (f32x16)0.f, Sb = (f32x16)0.f;
            #pragma unroll
            for (int kc = 0; kc < 4; ++kc)
                Sa = __builtin_amdgcn_mfma_f32_32x32x16_bf16(ka[kc], qf[kc], Sa, 0, 0, 0);
            #pragma unroll
            for (int kc = 0; kc < 4; ++kc)
                Sb = __builtin_amdgcn_mfma_f32_32x32x16_bf16(kb2[kc], qf[kc], Sb, 0, 0, 0);

            if (kv0 + 64 > q0) {  // only near-diagonal chunks need masking
                #pragma unroll
                for (int r = 0; r < 16; ++r) {
                    const int row = (r & 3) + 8 * (r >> 2) + 4 * hi;
                    if (kv0 + row > qabs)      Sa[r] = -1.0e30f;
                    if (kv0 + 32 + row > qabs) Sb[r] = -1.0e30f;
                }
            }

            float mx = -3.0e38f;
            #pragma unroll
            for (int r = 0; r < 16; ++r) mx = fmaxf(mx, fmaxf(Sa[r], Sb[r]));
            mx = fmaxf(mx, __shfl_xor(mx, 32));
            const float mnew = fmaxf(m, mx);
            const float fac = exp2f(m - mnew);
            float ps = 0.f;
            #pragma unroll
            for (int r = 0; r < 16; ++r) { Sa[r] = exp2f(Sa[r] - mnew); ps += Sa[r]; }
            #pragma unroll
            for (int r = 0; r < 16; ++r) { Sb[r] = exp2f(Sb[r] - mnew); ps += Sb[r]; }
            ps += __shfl_xor(ps, 32);
            l = l * fac + ps;
            m = mnew;
            #pragma unroll
            for (int r = 0; r < 16; ++r) { Oa[r] *= fac; Oc[r] *= fac; }

            // P^T -> bf16 B-fragments via cvt_pk + permlane32_swap (T12)
            bf16x8 F0, F1, F2, F3;
            {
                unsigned a0 = cvtpk(Sa[0], Sa[1]),  a1 = cvtpk(Sa[2], Sa[3]);
                unsigned a2 = cvtpk(Sa[4], Sa[5]),  a3 = cvtpk(Sa[6], Sa[7]);
                plswap(a0, a2); plswap(a1, a3);
                u32x4 w0; w0[0]=a0; w0[1]=a1; w0[2]=a2; w0[3]=a3;
                F0 = __builtin_bit_cast(bf16x8, w0);
                unsigned b0 = cvtpk(Sa[8], Sa[9]),  b1 = cvtpk(Sa[10], Sa[11]);
                unsigned b2 = cvtpk(Sa[12], Sa[13]), b3 = cvtpk(Sa[14], Sa[15]);
                plswap(b0, b2); plswap(b1, b3);
                u32x4 w1; w1[0]=b0; w1[1]=b1; w1[2]=b2; w1[3]=b3;
                F1 = __builtin_bit_cast(bf16x8, w1);
                unsigned c0 = cvtpk(Sb[0], Sb[1]),  c1 = cvtpk(Sb[2], Sb[3]);
                unsigned c2 = cvtpk(Sb[4], Sb[5]),  c3 = cvtpk(Sb[6], Sb[7]);
                plswap(c0, c2); plswap(c1, c3);
                u32x4 w2; w2[0]=c0; w2[1]=c1; w2[2]=c2; w2[3]=c3;
                F2 = __builtin_bit_cast(bf16x8, w2);
                unsigned d0 = cvtpk(Sb[8], Sb[9]),  d1 = cvtpk(Sb[10], Sb[11]);
                unsigned d2 = cvtpk(Sb[12], Sb[13]), d3 = cvtpk(Sb[14], Sb[15]);
                plswap(d0, d2); plswap(d1, d3);
                u32x4 w3; w3[0]=d0; w3[1]=d1; w3[2]=d2; w3[3]=d3;
                F3 = __builtin_bit_cast(bf16x8, w3);
            }
            const __hip_bfloat16* vbase = Vt + (size_t)l31 * N_TOK + kv0 + 8 * hi;
            bf16x8 Fa[4] = {F0, F1, F2, F3};
            #pragma unroll
            for (int ks = 0; ks < 4; ++ks) {
                bf16x8 v0 = *reinterpret_cast<const bf16x8*>(vbase + ks * 16);
                bf16x8 v1 = *reinterpret_cast<const bf16x8*>(vbase + (size_t)32 * N_TOK + ks * 16);
                Oa = __builtin_amdgcn_mfma_f32_32x32x16_bf16(v0, Fa[ks], Oa, 0, 0, 0);
                Oc = __builtin_amdgcn_mfma_f32_32x32x16_bf16(v1, Fa[ks], Oc, 0, 0, 0);
            }
        }

        if (hi == 0) { sM[w][l31] = m; sL[w][l31] = l; }
        #pragma unroll
        for (int r = 0; r < 16; ++r) {
            const int d = (r & 3) + 8 * (r >> 2) + 4 * hi;
            sO[w][d][l31]      = Oa[r];
            sO[w][d + 32][l31] = Oc[r];
        }
        __syncthreads();

        float* pb = Part + (size_t)(t * 2 + s) * 2112;
        for (int e = tid; e < 2048; e += 512) {
            const int d = e >> 5, qq = e & 31;
            float mb = -3.0e38f;
            #pragma unroll
            for (int wi = 0; wi < 8; ++wi) mb = fmaxf(mb, sM[wi][qq]);
            float lb = 0.f, ob = 0.f;
            #pragma unroll
            for (int wi = 0; wi < 8; ++wi) {
                const float sc = exp2f(sM[wi][qq] - mb);
                lb += sL[wi][qq] * sc;
                ob += sO[wi][d][qq] * sc;
            }
            pb[e] = ob;
            if (d == 0) { pb[2048 + qq] = mb; pb[2080 + qq] = lb; }
        }
        __syncthreads();
    }
}

// ---------------- kernel 2b: merge the 2 kv-split partials ---------
__global__ __launch_bounds__(256) void merge_kernel(
    const float* __restrict__ Part, __hip_bfloat16* __restrict__ Ob) {
    const int t = blockIdx.x, q0 = t * 32;
    const float* p0 = Part + (size_t)(t * 2) * 2112;
    const float* p1 = p0 + 2112;
    for (int e = threadIdx.x; e < 2048; e += 256) {
        const int qq = e >> 6, d = e & 63;
        const float m0 = p0[2048 + qq], m1 = p1[2048 + qq];
        const float mm = fmaxf(m0, m1);
        const float s0 = exp2f(m0 - mm), s1 = exp2f(m1 - mm);
        const float ll = p0[2080 + qq] * s0 + p1[2080 + qq] * s1;
        const float o = (p0[d * 32 + qq] * s0 + p1[d * 32 + qq] * s1) / ll;
        Ob[(size_t)(q0 + qq) * 64 + d] = __float2bfloat16(o);
    }
}

// ---------------- kernel 3: out = O @ Wout + bout ------------------
__global__ __launch_bounds__(256) void out_kernel(
    const __hip_bfloat16* __restrict__ Ob,
    const __hip_bfloat16* __restrict__ WoT,
    const float* __restrict__ bout,
    float* __restrict__ out) {
    const int tid = threadIdx.x;
    const int w = tid >> 6, lane = tid & 63;
    const int l16 = lane & 15, lq = lane >> 4;
    const int m0 = blockIdx.x * 64 + w * 16;
    const int n0 = blockIdx.y * 256;

    const __hip_bfloat16* orow = Ob + (size_t)(m0 + l16) * 64;
    bf16x8 a0 = *reinterpret_cast<const bf16x8*>(orow + 8 * lq);
    bf16x8 a1 = *reinterpret_cast<const bf16x8*>(orow + 32 + 8 * lq);

    for (int nt = 0; nt < 16; ++nt) {
        const __hip_bfloat16* wrow = WoT + (size_t)(n0 + nt * 16 + l16) * 64;
        bf16x8 b0 = *reinterpret_cast<const bf16x8*>(wrow + 8 * lq);
        bf16x8 b1 = *reinterpret_cast<const bf16x8*>(wrow + 32 + 8 * lq);
        f32x4 acc = (f32x4)0.f;
        acc = __builtin_amdgcn_mfma_f32_16x16x32_bf16(a0, b0, acc, 0, 0, 0);
        acc = __builtin_amdgcn_mfma_f32_16x16x32_bf16(a1, b1, acc, 0, 0, 0);
        int col = n0 + nt * 16 + l16;
        float bb = bout[col];
        #pragma unroll
        for (int r = 0; r < 4; ++r) {
            int row = m0 + 4 * lq + r;
            out[(size_t)row * 1024 + col] = acc[r] + bb;
        }
    }
}

// ---------------- launch -------------------------------------------
extern "C" void kernel_launch(void* const* d_in, const int* in_sizes, int n_in,
                              void* d_out, int out_size, void* d_ws, size_t ws_size,
                              hipStream_t stream) {
    const float* x    = (const float*)d_in[0];
    const float* Wqkv = (const float*)d_in[1];
    const float* Wout = (const float*)d_in[2];
    const float* bout = (const float*)d_in[3];
    float* out = (float*)d_out;

    char* ws = (char*)d_ws;
    __hip_bfloat16* Wt  = (__hip_bfloat16*)(ws);                 // 393216 B
    __hip_bfloat16* WoT = (__hip_bfloat16*)(ws + 393216);        // 131072 B
    __hip_bfloat16* Qb  = (__hip_bfloat16*)(ws + 524288);        // 1 MiB
    __hip_bfloat16* Kb  = (__hip_bfloat16*)(ws + 1572864);       // 1 MiB
    __hip_bfloat16* Vt  = (__hip_bfloat16*)(ws + 2621440);       // 1 MiB
    __hip_bfloat16* Ob  = (__hip_bfloat16*)(ws + 3670016);       // 1 MiB
    float*          Part = (float*)(ws + 4718592);               // 4.33 MB

    conv_kernel<<<1024, 256, 0, stream>>>(Wqkv, Wout, Wt, WoT);
    qkv_kernel<<<256, 256, 0, stream>>>(x, Wt, Qb, Kb, Vt);
    attn_kernel<<<256, 512, 0, stream>>>(Qb, Kb, Vt, Part);
    merge_kernel<<<256, 256, 0, stream>>>(Part, Ob);
    out_kernel<<<dim3(128, 4), 256, 0, stream>>>(Ob, WoT, bout, out);
}